// Round 2
// baseline (340.300 us; speedup 1.0000x reference)
//
#include <hip/hip_runtime.h>
#include <hip/hip_bf16.h>

#define HDIM 2048
#define DDIM 128
#define NT 256        // kv (0..127) | gate (128..255)
#define BM 64
#define BK 32
#define LDK 40        // padded LDS leading dim (80 B rows, 16B-aligned)
#define MT 16384      // B*S rows
#define TCH 64

typedef __attribute__((ext_vector_type(8))) short bf16x8_t;
typedef __attribute__((ext_vector_type(4))) float f32x4_t;

// ---------------- kernel D: detect input dtype (1 = fp32, 0 = bf16) -------------------
// fp32 data viewed as u16: even halves have uniform-random "exponent" bits -> huge bf16s.
// genuine bf16 N(0,1) data never has exponent >= 167 (|x| > 2^40).
__global__ void k_detect(const unsigned short* __restrict__ h, int* __restrict__ flag) {
  int bad = 0;
  for (int i = threadIdx.x; i < 8192; i += 256) {
    int e = (h[i] >> 7) & 0xFF;
    bad |= (e >= 167) ? 1 : 0;
  }
  __shared__ int s;
  if (threadIdx.x == 0) s = 0;
  __syncthreads();
  if (bad) atomicOr(&s, 1);
  __syncthreads();
  if (threadIdx.x == 0) *flag = s;
}

// ---------------- kernel 0: transpose+convert w_kv / w_gate into Wt[256][2048] bf16 ---
__global__ void k_prep(const void* __restrict__ w_kv, const void* __restrict__ w_gate,
                       const int* __restrict__ flag, __hip_bfloat16* __restrict__ Wt) {
  __shared__ float tile[64][65];
  const int isF32 = *flag;
  const void* src = blockIdx.z ? w_gate : w_kv;
  const int k0 = blockIdx.x * 64;
  const int n0 = blockIdx.y * 64;
  const int tx = threadIdx.x & 63;
  const int ty = threadIdx.x >> 6;  // 0..3
#pragma unroll
  for (int i = 0; i < 16; ++i) {
    int r = i * 4 + ty;
    int idx = (k0 + r) * DDIM + n0 + tx;
    float v = isF32 ? ((const float*)src)[idx]
                    : __bfloat162float(((const __hip_bfloat16*)src)[idx]);
    tile[tx][r] = v;
  }
  __syncthreads();
#pragma unroll
  for (int i = 0; i < 16; ++i) {
    int r = i * 4 + ty;
    Wt[(blockIdx.z * DDIM + n0 + r) * HDIM + k0 + tx] = __float2bfloat16(tile[r][tx]);
  }
}

// ---------------- kernel 1: C[16384][256] = hidden @ [w_kv | w_gate] (bf16 MFMA) ------
// Block tile 64(m) x 256(n), 4 waves each 64x64. A staged to LDS (converted to bf16);
// B fragments loaded directly from L2-resident Wt. Register prefetch of next A tile.
__global__ __launch_bounds__(256)
void k_gemm(const void* __restrict__ hidden, const __hip_bfloat16* __restrict__ Wt,
            const int* __restrict__ flag, __hip_bfloat16* __restrict__ C) {
  __shared__ __align__(16) __hip_bfloat16 As[BM * LDK];
  const int isF32 = *flag;
  const int tid  = threadIdx.x;
  const int bm0  = blockIdx.x * BM;
  const int wave = tid >> 6;
  const int lane = tid & 63;
  const int wn   = wave * 64;        // this wave's 64 output columns
  const int lrow = lane & 15;
  const int quad = lane >> 4;

  f32x4_t acc[4][4];
#pragma unroll
  for (int i = 0; i < 4; ++i)
#pragma unroll
    for (int j = 0; j < 4; ++j) acc[i][j] = (f32x4_t){0.f, 0.f, 0.f, 0.f};

  // staging role: row = tid>>2 (0..63), k-segment = (tid&3)*8
  const int srow = tid >> 2;
  const int skg  = (tid & 3) * 8;
  const float*          Af = (const float*)hidden + (size_t)(bm0 + srow) * HDIM + skg;
  const unsigned short* Ab = (const unsigned short*)hidden + (size_t)(bm0 + srow) * HDIM + skg;

  float4 pa0, pa1;  // fp32-path prefetch
  int4   pb;        // bf16-path prefetch
  if (isF32) { pa0 = *(const float4*)(Af); pa1 = *(const float4*)(Af + 4); }
  else       { pb = *(const int4*)(Ab); }

  for (int k0 = 0; k0 < HDIM; k0 += BK) {
    __syncthreads();  // previous iteration's LDS reads complete
    if (isF32) {
      union { int4 v; __hip_bfloat16 h[8]; } u;
      u.h[0] = __float2bfloat16(pa0.x); u.h[1] = __float2bfloat16(pa0.y);
      u.h[2] = __float2bfloat16(pa0.z); u.h[3] = __float2bfloat16(pa0.w);
      u.h[4] = __float2bfloat16(pa1.x); u.h[5] = __float2bfloat16(pa1.y);
      u.h[6] = __float2bfloat16(pa1.z); u.h[7] = __float2bfloat16(pa1.w);
      *(int4*)(As + srow * LDK + skg) = u.v;
    } else {
      *(int4*)(As + srow * LDK + skg) = pb;
    }
    __syncthreads();

    // prefetch next K tile into registers (issued before the compute of this tile)
    if (k0 + BK < HDIM) {
      if (isF32) { pa0 = *(const float4*)(Af + k0 + BK); pa1 = *(const float4*)(Af + k0 + BK + 4); }
      else       { pb = *(const int4*)(Ab + k0 + BK); }
    }

    bf16x8_t bfrag[4], afrag[4];
#pragma unroll
    for (int nt = 0; nt < 4; ++nt)   // B frag: col = lane&15, k = quad*8 + j
      bfrag[nt] = *(const bf16x8_t*)(Wt + (size_t)(wn + nt * 16 + lrow) * HDIM + k0 + quad * 8);
#pragma unroll
    for (int mt = 0; mt < 4; ++mt)   // A frag: row = lane&15, k = quad*8 + j
      afrag[mt] = *(const bf16x8_t*)(As + (mt * 16 + lrow) * LDK + quad * 8);
#pragma unroll
    for (int mt = 0; mt < 4; ++mt)
#pragma unroll
      for (int nt = 0; nt < 4; ++nt)
        acc[mt][nt] = __builtin_amdgcn_mfma_f32_16x16x32_bf16(afrag[mt], bfrag[nt], acc[mt][nt], 0, 0, 0);
  }

  // C/D layout (m89/m91-verified): row = quad*4 + reg, col = lane&15
#pragma unroll
  for (int mt = 0; mt < 4; ++mt) {
    const int mrow = bm0 + mt * 16 + quad * 4;
#pragma unroll
    for (int nt = 0; nt < 4; ++nt) {
      const int ncol = wn + nt * 16 + lrow;
#pragma unroll
      for (int r = 0; r < 4; ++r)
        C[(size_t)(mrow + r) * NT + ncol] = __float2bfloat16(acc[mt][nt][r]);
    }
  }
}

// ---------------- kernel 2: softmax-compress + RMSNorm + RoPE -------------------------
__global__ void k_compress(const __hip_bfloat16* __restrict__ C,      // [MT][NT] bf16
                           const void* __restrict__ pbias,            // [128][128]
                           const void* __restrict__ nw,               // [128]
                           const int* __restrict__ flag,
                           void* __restrict__ out) {                  // [128*128]
  const int isF32 = *flag;
  const int j  = threadIdx.x;       // d index 0..127
  const int bt = blockIdx.x;        // b*TCH + t
  const int t  = bt & (TCH - 1);
  const long i0 = (long)bt * 128;

  // online softmax over the m=128 compress positions
  float mx = -3.0e38f, l = 0.f, acc = 0.f;
  for (int r = 0; r < 128; ++r) {
    const __hip_bfloat16* row = C + (i0 + r) * NT;
    float pb = isF32 ? ((const float*)pbias)[r * DDIM + j]
                     : __bfloat162float(((const __hip_bfloat16*)pbias)[r * DDIM + j]);
    float g = __bfloat162float(row[DDIM + j]) + pb;
    float v = __bfloat162float(row[j]);
    float nm = fmaxf(mx, g);
    float sc = __expf(mx - nm);
    float e  = __expf(g - nm);
    l   = l * sc + e;
    acc = acc * sc + e * v;
    mx  = nm;
  }
  float comp = acc / l;

  // RMS norm across the 128 columns (2 waves)
  float sq = comp * comp;
#pragma unroll
  for (int off = 32; off > 0; off >>= 1) sq += __shfl_down(sq, off, 64);
  __shared__ float ssum[2];
  __shared__ float sh[DDIM];
  if ((j & 63) == 0) ssum[j >> 6] = sq;
  __syncthreads();
  float var = (ssum[0] + ssum[1]) * (1.0f / DDIM);
  float wv = isF32 ? ((const float*)nw)[j] : __bfloat162float(((const __hip_bfloat16*)nw)[j]);
  float y = comp * rsqrtf(var + 1e-6f) * wv;
  sh[j] = y;
  __syncthreads();

  float outv = y;  // nope part (j < 64)
  if (j >= 64) {
    int jj = j - 64;             // rope index 0..63
    int fi = jj >> 1;            // repeat(cos,2): freq index
    double invf = exp((double)fi * (-0.28782313662425575));  // 10000^(-fi/32)
    double ang  = (double)(t * 128) * invf;
    float c = (float)cos(ang);
    float s = (float)sin(ang);
    float other = (jj < 32) ? -sh[64 + jj + 32] : sh[64 + jj - 32];  // rotate_half
    outv = y * c + other * s;
  }
  if (isF32) ((float*)out)[bt * DDIM + j] = outv;
  else       ((__hip_bfloat16*)out)[bt * DDIM + j] = __float2bfloat16(outv);
}

// ---------------- host ----------------------------------------------------------------
extern "C" void kernel_launch(void* const* d_in, const int* in_sizes, int n_in,
                              void* d_out, int out_size, void* d_ws, size_t ws_size,
                              hipStream_t stream) {
  const void* hidden = d_in[0];
  // d_in[1] q_residual, d_in[2] position_ids: unused by the reference
  const void* w_kv   = d_in[3];
  const void* w_gate = d_in[4];
  const void* pbias  = d_in[5];
  const void* nw     = d_in[6];

  // ws layout: [0] flag (int), [256 B) Wt bf16 1 MiB, [256 B + 1 MiB) C bf16 8 MiB
  int* flag = (int*)d_ws;
  __hip_bfloat16* Wt = (__hip_bfloat16*)((char*)d_ws + 256);
  __hip_bfloat16* C  = (__hip_bfloat16*)((char*)d_ws + 256 + (size_t)NT * HDIM * sizeof(__hip_bfloat16));

  k_detect<<<1, 256, 0, stream>>>((const unsigned short*)hidden, flag);
  k_prep<<<dim3(HDIM / 64, DDIM / 64, 2), 256, 0, stream>>>(w_kv, w_gate, flag, Wt);
  k_gemm<<<dim3(MT / BM), 256, 0, stream>>>(hidden, Wt, flag, C);
  k_compress<<<dim3(128), DDIM, 0, stream>>>(C, pbias, nw, flag, d_out);
}